// Round 1
// baseline (1139.092 us; speedup 1.0000x reference)
//
#include <hip/hip_runtime.h>
#include <hip/hip_bf16.h>

#define BN_EPS 1e-5f

// ---------------- degree / normalization ----------------
__global__ void k_count_deg(const int* __restrict__ dst, int E, int* __restrict__ deg) {
    int i = blockIdx.x * blockDim.x + threadIdx.x;
    if (i < E) atomicAdd(&deg[dst[i]], 1);
}

__global__ void k_dis(const int* __restrict__ deg, int n, float* __restrict__ dis) {
    int i = blockIdx.x * blockDim.x + threadIdx.x;
    if (i < n) dis[i] = rsqrtf((float)(deg[i] + 1));   // +1 self-loop, deg>=1 always
}

// ---------------- dense transform: out[n][64] = X[n][64] @ W[64][64] ----------------
__global__ void k_matmul64(const float* __restrict__ X, const float* __restrict__ W,
                           int n, float* __restrict__ out) {
    __shared__ float Ws[64 * 64];
    int tid = threadIdx.x;
    #pragma unroll
    for (int i = tid; i < 4096; i += 256) Ws[i] = W[i];
    __syncthreads();
    int lane = tid & 63;
    int wave = tid >> 6;
    int row = blockIdx.x * 4 + wave;
    if (row >= n) return;
    float xv = X[(size_t)row * 64 + lane];
    float acc = 0.f;
    #pragma unroll
    for (int k = 0; k < 64; ++k) {
        float xk = __shfl(xv, k);          // broadcast X[row][k] across the wave
        acc = fmaf(xk, Ws[k * 64 + lane], acc);
    }
    out[(size_t)row * 64 + lane] = acc;
}

// ---------------- aggregation ----------------
// a[n][c] = t[n][c] * dis[n]^2   (self-loop term, also zero-initializes accumulator)
__global__ void k_selfloop(const float* __restrict__ t, const float* __restrict__ dis,
                           int n, float* __restrict__ a) {
    int i = blockIdx.x * blockDim.x + threadIdx.x;
    if (i < n * 64) {
        int r = i >> 6;
        float d = dis[r];
        a[i] = t[i] * d * d;
    }
}

// a[dst][c] += t[src][c] * dis[src]*dis[dst]  for each edge (64 lanes = 64 features)
__global__ void k_scatter(const int* __restrict__ src, const int* __restrict__ dst,
                          const float* __restrict__ dis, const float* __restrict__ t,
                          int E, float* __restrict__ a) {
    int idx = blockIdx.x * blockDim.x + threadIdx.x;
    int e = idx >> 6;
    int c = idx & 63;
    if (e < E) {
        int s = src[e], d = dst[e];
        float w = dis[s] * dis[d];
        atomicAdd(&a[(size_t)d * 64 + c], t[(size_t)s * 64 + c] * w);
    }
}

// ---------------- BatchNorm ----------------
// stats[0..63] = column sums, stats[64..127] = column sum-of-squares
__global__ void k_stats(const float* __restrict__ a, int n, float* __restrict__ stats) {
    int c = threadIdx.x & 63;
    int grp = threadIdx.x >> 6;               // 0..3
    float s = 0.f, s2 = 0.f;
    for (int r = blockIdx.x * 4 + grp; r < n; r += gridDim.x * 4) {
        float v = a[(size_t)r * 64 + c];
        s += v; s2 += v * v;
    }
    __shared__ float sh[2][4][64];
    sh[0][grp][c] = s; sh[1][grp][c] = s2;
    __syncthreads();
    if (threadIdx.x < 64) {
        float S  = sh[0][0][c] + sh[0][1][c] + sh[0][2][c] + sh[0][3][c];
        float S2 = sh[1][0][c] + sh[1][1][c] + sh[1][2][c] + sh[1][3][c];
        atomicAdd(&stats[c], S);
        atomicAdd(&stats[64 + c], S2);
    }
}

// bnp[c] = gamma*rsqrt(var+eps); bnp[64+c] = beta - mean*scale  (bias b cancels in BN)
__global__ void k_bnparams(const float* __restrict__ stats, const float* __restrict__ g,
                           const float* __restrict__ bt, int n, float* __restrict__ bnp) {
    int c = threadIdx.x;
    if (c < 64) {
        float inv_n = 1.f / (float)n;
        float mean = stats[c] * inv_n;
        float var = stats[64 + c] * inv_n - mean * mean;
        float s = g[c] * rsqrtf(var + BN_EPS);
        bnp[c] = s;
        bnp[64 + c] = bt[c] - mean * s;
    }
}

__global__ void k_bnrelu(const float* __restrict__ a, const float* __restrict__ bnp,
                         int n, float* __restrict__ h) {
    int i = blockIdx.x * blockDim.x + threadIdx.x;
    if (i < n * 64) {
        int c = i & 63;
        h[i] = fmaxf(0.f, fmaf(a[i], bnp[c], bnp[64 + c]));
    }
}

// ---------------- global mean pool ----------------
__global__ void k_pool(const float* __restrict__ h, const int* __restrict__ batch,
                       int n, float* __restrict__ pools, int* __restrict__ pcnt) {
    int idx = blockIdx.x * blockDim.x + threadIdx.x;
    int r = idx >> 6;
    int c = idx & 63;
    if (r < n) {
        int g = batch[r];
        atomicAdd(&pools[(size_t)g * 64 + c], h[(size_t)r * 64 + c]);
        if (c == 0) atomicAdd(&pcnt[g], 1);
    }
}

__global__ void k_poolout(const float* __restrict__ pools, const int* __restrict__ pcnt,
                          int G, float* __restrict__ out) {
    int i = blockIdx.x * blockDim.x + threadIdx.x;
    if (i < G * 64) {
        int g = i >> 6;
        float cnt = (float)max(pcnt[g], 1);
        out[i] = pools[i] / cnt;
    }
}

// ---------------- launch ----------------
extern "C" void kernel_launch(void* const* d_in, const int* in_sizes, int n_in,
                              void* d_out, int out_size, void* d_ws, size_t ws_size,
                              hipStream_t stream) {
    const float* x     = (const float*)d_in[0];
    const int*   ei    = (const int*)d_in[1];
    const int*   batch = (const int*)d_in[2];
    const float* W1    = (const float*)d_in[3];
    // d_in[4] = b1 : cancels inside BatchNorm, unused
    const float* g1    = (const float*)d_in[5];
    const float* bt1   = (const float*)d_in[6];
    const float* W2    = (const float*)d_in[7];
    // d_in[8] = b2 : cancels, unused
    const float* g2    = (const float*)d_in[9];
    const float* bt2   = (const float*)d_in[10];

    const int N = in_sizes[0] / 64;
    const int E = in_sizes[1] / 2;
    const int G = out_size / 64;

    const int* src = ei;
    const int* dst = ei + E;

    float* t     = (float*)d_ws;                   // N*64
    float* a     = t + (size_t)N * 64;             // N*64
    float* h     = a + (size_t)N * 64;             // N*64
    float* dis   = h + (size_t)N * 64;             // N
    int*   deg   = (int*)(dis + N);                // N
    float* stats = (float*)(deg + N);              // 128
    float* bnp   = stats + 128;                    // 128
    float* pools = bnp + 128;                      // G*64
    int*   pcnt  = (int*)(pools + (size_t)G * 64); // G

    float* out = (float*)d_out;

    const int mmBlocks = (N + 3) / 4;
    const int ewBlocks = (int)(((size_t)N * 64 + 255) / 256);
    const int scBlocks = (int)(((size_t)E * 64 + 255) / 256);

    // degree & normalization
    hipMemsetAsync(deg, 0, (size_t)N * sizeof(int), stream);
    k_count_deg<<<(E + 255) / 256, 256, 0, stream>>>(dst, E, deg);
    k_dis<<<(N + 255) / 256, 256, 0, stream>>>(deg, N, dis);

    // ---- layer 1 ----
    k_matmul64<<<mmBlocks, 256, 0, stream>>>(x, W1, N, t);
    k_selfloop<<<ewBlocks, 256, 0, stream>>>(t, dis, N, a);
    k_scatter<<<scBlocks, 256, 0, stream>>>(src, dst, dis, t, E, a);
    hipMemsetAsync(stats, 0, 128 * sizeof(float), stream);
    k_stats<<<512, 256, 0, stream>>>(a, N, stats);
    k_bnparams<<<1, 64, 0, stream>>>(stats, g1, bt1, N, bnp);
    k_bnrelu<<<ewBlocks, 256, 0, stream>>>(a, bnp, N, h);

    // ---- layer 2 ----
    k_matmul64<<<mmBlocks, 256, 0, stream>>>(h, W2, N, t);
    k_selfloop<<<ewBlocks, 256, 0, stream>>>(t, dis, N, a);
    k_scatter<<<scBlocks, 256, 0, stream>>>(src, dst, dis, t, E, a);
    hipMemsetAsync(stats, 0, 128 * sizeof(float), stream);
    k_stats<<<512, 256, 0, stream>>>(a, N, stats);
    k_bnparams<<<1, 64, 0, stream>>>(stats, g2, bt2, N, bnp);
    k_bnrelu<<<ewBlocks, 256, 0, stream>>>(a, bnp, N, h);

    // ---- pool ----
    hipMemsetAsync(pools, 0, ((size_t)G * 64 + G) * sizeof(float), stream);
    k_pool<<<ewBlocks, 256, 0, stream>>>(h, batch, N, pools, pcnt);
    k_poolout<<<(G * 64 + 255) / 256, 256, 0, stream>>>(pools, pcnt, G, out);
}

// Round 2
// 720.389 us; speedup vs baseline: 1.5812x; 1.5812x over previous
//
#include <hip/hip_runtime.h>
#include <hip/hip_bf16.h>

#define BN_EPS 1e-5f

// ---------------- degree / normalization ----------------
__global__ void k_count_deg(const int* __restrict__ dst, int E, int* __restrict__ deg) {
    int i = blockIdx.x * blockDim.x + threadIdx.x;
    if (i < E) atomicAdd(&deg[dst[i]], 1);
}

__global__ void k_dis(const int* __restrict__ deg, int n, float* __restrict__ dis) {
    int i = blockIdx.x * blockDim.x + threadIdx.x;
    if (i < n) dis[i] = rsqrtf((float)(deg[i] + 1));   // +1 self-loop
}

// ---------------- CSR build: exclusive scan of deg ----------------
// scanA: each block sums 1024 elements (thread t owns deg[base+4t .. +3])
__global__ void k_scanA(const int* __restrict__ deg, int n, int* __restrict__ bsum) {
    __shared__ int sh[256];
    int base = blockIdx.x * 1024 + threadIdx.x * 4;
    int s = 0;
    #pragma unroll
    for (int k = 0; k < 4; ++k) { int i = base + k; if (i < n) s += deg[i]; }
    sh[threadIdx.x] = s;
    __syncthreads();
    for (int off = 128; off > 0; off >>= 1) {
        if (threadIdx.x < off) sh[threadIdx.x] += sh[threadIdx.x + off];
        __syncthreads();
    }
    if (threadIdx.x == 0) bsum[blockIdx.x] = sh[0];
}

__global__ void k_scanB(int* __restrict__ bsum, int nb) {
    if (threadIdx.x == 0) {
        int run = 0;
        for (int i = 0; i < nb; ++i) { int v = bsum[i]; bsum[i] = run; run += v; }
    }
}

// scanC: exclusive prefix within block + block offset -> rowptr, nextpos
__global__ void k_scanC(const int* __restrict__ deg, const int* __restrict__ bsum,
                        int n, int E, int* __restrict__ rowptr, int* __restrict__ nextpos) {
    __shared__ int sh[256];
    int tid = threadIdx.x;
    int base = blockIdx.x * 1024 + tid * 4;
    int v[4]; int tsum = 0;
    #pragma unroll
    for (int k = 0; k < 4; ++k) {
        int i = base + k;
        v[k] = (i < n) ? deg[i] : 0;
        tsum += v[k];
    }
    sh[tid] = tsum;
    __syncthreads();
    // Hillis-Steele inclusive scan over 256 thread sums
    for (int off = 1; off < 256; off <<= 1) {
        int add = (tid >= off) ? sh[tid - off] : 0;
        __syncthreads();
        sh[tid] += add;
        __syncthreads();
    }
    int excl = bsum[blockIdx.x] + sh[tid] - tsum;   // exclusive prefix for first elem of thread
    #pragma unroll
    for (int k = 0; k < 4; ++k) {
        int i = base + k;
        if (i < n) { rowptr[i] = excl; nextpos[i] = excl; }
        excl += v[k];
    }
    if (blockIdx.x == 0 && tid == 0) rowptr[n] = E;
}

// fill: cs2[pos] = {src, weight}
__global__ void k_fill(const int* __restrict__ src, const int* __restrict__ dst,
                       const float* __restrict__ dis, int E,
                       int* __restrict__ nextpos, int2* __restrict__ cs2) {
    int i = blockIdx.x * blockDim.x + threadIdx.x;
    if (i < E) {
        int s = src[i], d = dst[i];
        float w = dis[s] * dis[d];
        int pos = atomicAdd(&nextpos[d], 1);
        cs2[pos] = make_int2(s, __float_as_int(w));
    }
}

// ---------------- dense transform: out[n][64] = f(X[n])[64] @ W[64][64] ----------------
// bnp != nullptr applies relu(x*s[c]+o[c]) to input elements first (fused BN+ReLU)
__global__ void k_matmul64(const float* __restrict__ X, const float* __restrict__ W,
                           const float* __restrict__ bnp, int n, float* __restrict__ out) {
    __shared__ float Ws[64 * 64];
    int tid = threadIdx.x;
    #pragma unroll
    for (int i = tid; i < 4096; i += 256) Ws[i] = W[i];
    __syncthreads();
    int lane = tid & 63;
    int wave = tid >> 6;
    int row = blockIdx.x * 4 + wave;
    if (row >= n) return;
    float xv = X[(size_t)row * 64 + lane];
    if (bnp) xv = fmaxf(0.f, fmaf(xv, bnp[lane], bnp[64 + lane]));
    float acc = 0.f;
    #pragma unroll
    for (int k = 0; k < 64; ++k) {
        float xk = __shfl(xv, k);
        acc = fmaf(xk, Ws[k * 64 + lane], acc);
    }
    out[(size_t)row * 64 + lane] = acc;
}

// ---------------- aggregation: one wave per dst node, register accumulation ----------------
__global__ void k_gather(const int2* __restrict__ cs2, const int* __restrict__ rowptr,
                         const float* __restrict__ dis, const float* __restrict__ t,
                         int n, float* __restrict__ a) {
    int lane = threadIdx.x & 63;
    int wave = threadIdx.x >> 6;
    int row = blockIdx.x * 4 + wave;
    if (row >= n) return;
    int e0 = rowptr[row], e1 = rowptr[row + 1];
    float acc = 0.f;
    for (int base = e0; base < e1; base += 64) {
        int cnt = min(64, e1 - base);
        int2 p = (lane < cnt) ? cs2[base + lane] : make_int2(0, 0);
        for (int j = 0; j < cnt; ++j) {
            int   s = __shfl(p.x, j);
            float w = __int_as_float(__shfl(p.y, j));
            acc = fmaf(t[(size_t)s * 64 + lane], w, acc);
        }
    }
    float d = dis[row];
    a[(size_t)row * 64 + lane] = fmaf(t[(size_t)row * 64 + lane], d * d, acc);
}

// ---------------- BatchNorm stats ----------------
__global__ void k_stats(const float* __restrict__ a, int n, float* __restrict__ stats) {
    int c = threadIdx.x & 63;
    int grp = threadIdx.x >> 6;
    float s = 0.f, s2 = 0.f;
    for (int r = blockIdx.x * 4 + grp; r < n; r += gridDim.x * 4) {
        float v = a[(size_t)r * 64 + c];
        s += v; s2 += v * v;
    }
    __shared__ float sh[2][4][64];
    sh[0][grp][c] = s; sh[1][grp][c] = s2;
    __syncthreads();
    if (threadIdx.x < 64) {
        float S  = sh[0][0][c] + sh[0][1][c] + sh[0][2][c] + sh[0][3][c];
        float S2 = sh[1][0][c] + sh[1][1][c] + sh[1][2][c] + sh[1][3][c];
        atomicAdd(&stats[c], S);
        atomicAdd(&stats[64 + c], S2);
    }
}

__global__ void k_bnparams(const float* __restrict__ stats, const float* __restrict__ g,
                           const float* __restrict__ bt, int n, float* __restrict__ bnp) {
    int c = threadIdx.x;
    if (c < 64) {
        float inv_n = 1.f / (float)n;
        float mean = stats[c] * inv_n;
        float var = stats[64 + c] * inv_n - mean * mean;
        float s = g[c] * rsqrtf(var + BN_EPS);
        bnp[c] = s;
        bnp[64 + c] = bt[c] - mean * s;
    }
}

// ---------------- global mean pool (fused BN+ReLU on input) ----------------
__global__ void k_pool(const float* __restrict__ a, const float* __restrict__ bnp,
                       const int* __restrict__ batch, int n,
                       float* __restrict__ pools, int* __restrict__ pcnt) {
    int idx = blockIdx.x * blockDim.x + threadIdx.x;
    int r = idx >> 6;
    int c = idx & 63;
    if (r < n) {
        int g = batch[r];
        float v = fmaxf(0.f, fmaf(a[(size_t)r * 64 + c], bnp[c], bnp[64 + c]));
        atomicAdd(&pools[(size_t)g * 64 + c], v);
        if (c == 0) atomicAdd(&pcnt[g], 1);
    }
}

__global__ void k_poolout(const float* __restrict__ pools, const int* __restrict__ pcnt,
                          int G, float* __restrict__ out) {
    int i = blockIdx.x * blockDim.x + threadIdx.x;
    if (i < G * 64) {
        int g = i >> 6;
        float cnt = (float)max(pcnt[g], 1);
        out[i] = pools[i] / cnt;
    }
}

// ---------------- launch ----------------
extern "C" void kernel_launch(void* const* d_in, const int* in_sizes, int n_in,
                              void* d_out, int out_size, void* d_ws, size_t ws_size,
                              hipStream_t stream) {
    const float* x     = (const float*)d_in[0];
    const int*   ei    = (const int*)d_in[1];
    const int*   batch = (const int*)d_in[2];
    const float* W1    = (const float*)d_in[3];
    const float* g1    = (const float*)d_in[5];
    const float* bt1   = (const float*)d_in[6];
    const float* W2    = (const float*)d_in[7];
    const float* g2    = (const float*)d_in[9];
    const float* bt2   = (const float*)d_in[10];

    const int N = in_sizes[0] / 64;
    const int E = in_sizes[1] / 2;
    const int G = out_size / 64;

    const int* src = ei;
    const int* dst = ei + E;

    float* t       = (float*)d_ws;                      // N*64
    float* a       = t + (size_t)N * 64;                // N*64
    int2*  cs2     = (int2*)(a + (size_t)N * 64);       // E
    float* dis     = (float*)(cs2 + E);                 // N
    int*   deg     = (int*)(dis + N);                   // N
    int*   rowptr  = deg + N;                           // N+1
    int*   nextpos = rowptr + N + 1;                    // N
    int*   bsum    = nextpos + N;                       // <=1024
    float* stats   = (float*)(bsum + 1024);             // 128
    float* bnp     = stats + 128;                       // 128 (reused both layers)
    float* pools   = bnp + 128;                         // G*64
    int*   pcnt    = (int*)(pools + (size_t)G * 64);    // G

    float* out = (float*)d_out;

    const int NBLK = (N + 1023) / 1024;                 // scan blocks
    const int mmBlocks = (N + 3) / 4;
    const int ewBlocks = (int)(((size_t)N * 64 + 255) / 256);

    // ---- degree / norm / CSR build ----
    hipMemsetAsync(deg, 0, (size_t)N * sizeof(int), stream);
    k_count_deg<<<(E + 255) / 256, 256, 0, stream>>>(dst, E, deg);
    k_dis<<<(N + 255) / 256, 256, 0, stream>>>(deg, N, dis);
    k_scanA<<<NBLK, 256, 0, stream>>>(deg, N, bsum);
    k_scanB<<<1, 64, 0, stream>>>(bsum, NBLK);
    k_scanC<<<NBLK, 256, 0, stream>>>(deg, bsum, N, E, rowptr, nextpos);
    k_fill<<<(E + 255) / 256, 256, 0, stream>>>(src, dst, dis, E, nextpos, cs2);

    // ---- layer 1 ----
    k_matmul64<<<mmBlocks, 256, 0, stream>>>(x, W1, nullptr, N, t);
    k_gather<<<mmBlocks, 256, 0, stream>>>(cs2, rowptr, dis, t, N, a);
    hipMemsetAsync(stats, 0, 128 * sizeof(float), stream);
    k_stats<<<512, 256, 0, stream>>>(a, N, stats);
    k_bnparams<<<1, 64, 0, stream>>>(stats, g1, bt1, N, bnp);

    // ---- layer 2 (BN+ReLU of layer 1 fused into matmul input) ----
    k_matmul64<<<mmBlocks, 256, 0, stream>>>(a, W2, bnp, N, t);
    k_gather<<<mmBlocks, 256, 0, stream>>>(cs2, rowptr, dis, t, N, a);
    hipMemsetAsync(stats, 0, 128 * sizeof(float), stream);
    k_stats<<<512, 256, 0, stream>>>(a, N, stats);
    k_bnparams<<<1, 64, 0, stream>>>(stats, g2, bt2, N, bnp);

    // ---- pool (BN+ReLU of layer 2 fused) ----
    hipMemsetAsync(pools, 0, ((size_t)G * 64) * sizeof(float) + G * sizeof(int), stream);
    k_pool<<<ewBlocks, 256, 0, stream>>>(a, bnp, batch, N, pools, pcnt);
    k_poolout<<<(G * 64 + 255) / 256, 256, 0, stream>>>(pools, pcnt, G, out);
}

// Round 3
// 516.765 us; speedup vs baseline: 2.2043x; 1.3940x over previous
//
#include <hip/hip_runtime.h>
#include <hip/hip_bf16.h>

#define BN_EPS 1e-5f

// ---------------- degree / normalization ----------------
__global__ void k_count_deg(const int* __restrict__ dst, int E, int* __restrict__ deg) {
    int i = blockIdx.x * blockDim.x + threadIdx.x;
    if (i < E) atomicAdd(&deg[dst[i]], 1);
}

__global__ void k_dis(const int* __restrict__ deg, int n, float* __restrict__ dis) {
    int i = blockIdx.x * blockDim.x + threadIdx.x;
    if (i < n) dis[i] = rsqrtf((float)(deg[i] + 1));   // +1 self-loop
}

// ---------------- CSR build: exclusive scan of deg ----------------
__global__ void k_scanA(const int* __restrict__ deg, int n, int* __restrict__ bsum) {
    __shared__ int sh[256];
    int base = blockIdx.x * 1024 + threadIdx.x * 4;
    int s = 0;
    #pragma unroll
    for (int k = 0; k < 4; ++k) { int i = base + k; if (i < n) s += deg[i]; }
    sh[threadIdx.x] = s;
    __syncthreads();
    for (int off = 128; off > 0; off >>= 1) {
        if (threadIdx.x < off) sh[threadIdx.x] += sh[threadIdx.x + off];
        __syncthreads();
    }
    if (threadIdx.x == 0) bsum[blockIdx.x] = sh[0];
}

__global__ void k_scanB(int* __restrict__ bsum, int nb) {
    if (threadIdx.x == 0) {
        int run = 0;
        for (int i = 0; i < nb; ++i) { int v = bsum[i]; bsum[i] = run; run += v; }
    }
}

__global__ void k_scanC(const int* __restrict__ deg, const int* __restrict__ bsum,
                        int n, int E, int* __restrict__ rowptr, int* __restrict__ nextpos) {
    __shared__ int sh[256];
    int tid = threadIdx.x;
    int base = blockIdx.x * 1024 + tid * 4;
    int v[4]; int tsum = 0;
    #pragma unroll
    for (int k = 0; k < 4; ++k) {
        int i = base + k;
        v[k] = (i < n) ? deg[i] : 0;
        tsum += v[k];
    }
    sh[tid] = tsum;
    __syncthreads();
    for (int off = 1; off < 256; off <<= 1) {
        int add = (tid >= off) ? sh[tid - off] : 0;
        __syncthreads();
        sh[tid] += add;
        __syncthreads();
    }
    int excl = bsum[blockIdx.x] + sh[tid] - tsum;
    #pragma unroll
    for (int k = 0; k < 4; ++k) {
        int i = base + k;
        if (i < n) { rowptr[i] = excl; nextpos[i] = excl; }
        excl += v[k];
    }
    if (blockIdx.x == 0 && tid == 0) rowptr[n] = E;
}

__global__ void k_fill(const int* __restrict__ src, const int* __restrict__ dst,
                       const float* __restrict__ dis, int E,
                       int* __restrict__ nextpos, int2* __restrict__ cs2) {
    int i = blockIdx.x * blockDim.x + threadIdx.x;
    if (i < E) {
        int s = src[i], d = dst[i];
        float w = dis[s] * dis[d];
        int pos = atomicAdd(&nextpos[d], 1);
        cs2[pos] = make_int2(s, __float_as_int(w));
    }
}

// ---------------- tiled dense transform: out[64-tile][64] = f(X)[64-tile][64] @ W ----------------
// bnp != nullptr applies relu(x*s[c]+o[c]) to input first (fused BN+ReLU).
// Each thread computes a 4x4 micro-tile; X staged transposed in LDS.
__global__ void k_matmul64t(const float* __restrict__ X, const float* __restrict__ W,
                            const float* __restrict__ bnp, int n, float* __restrict__ out) {
    __shared__ float Xs[64][68];   // Xs[k][r] (transposed), stride 68 keeps b128 alignment
    __shared__ float Ws[64][64];
    const int tid = threadIdx.x;
    const int rowbase = blockIdx.x * 64;

    // load W (4096 floats) as float4
    {
        const float4* W4 = (const float4*)W;
        float4* Ws4 = (float4*)&Ws[0][0];
        #pragma unroll
        for (int k = 0; k < 4; ++k) Ws4[tid + 256 * k] = W4[tid + 256 * k];
    }
    // load X tile, apply optional BN+ReLU, store transposed
    {
        const int r  = tid >> 2;           // 0..63
        const int c0 = (tid & 3) * 16;     // 0,16,32,48
        const int row = rowbase + r;
        #pragma unroll
        for (int j = 0; j < 4; ++j) {
            float4 v;
            if (row < n) v = *(const float4*)&X[(size_t)row * 64 + c0 + 4 * j];
            else v = make_float4(0.f, 0.f, 0.f, 0.f);
            float vv[4] = {v.x, v.y, v.z, v.w};
            #pragma unroll
            for (int i = 0; i < 4; ++i) {
                int c = c0 + 4 * j + i;
                float f = vv[i];
                if (bnp) f = fmaxf(0.f, fmaf(f, bnp[c], bnp[64 + c]));
                Xs[c][r] = f;
            }
        }
    }
    __syncthreads();

    const int r0 = (tid & 15) * 4;
    const int c0 = (tid >> 4) * 4;
    float acc[4][4];
    #pragma unroll
    for (int i = 0; i < 4; ++i)
        #pragma unroll
        for (int j = 0; j < 4; ++j) acc[i][j] = 0.f;

    #pragma unroll 4
    for (int k = 0; k < 64; ++k) {
        float4 xv = *(const float4*)&Xs[k][r0];
        float4 wv = *(const float4*)&Ws[k][c0];
        float xa[4] = {xv.x, xv.y, xv.z, xv.w};
        float wa[4] = {wv.x, wv.y, wv.z, wv.w};
        #pragma unroll
        for (int i = 0; i < 4; ++i)
            #pragma unroll
            for (int j = 0; j < 4; ++j)
                acc[i][j] = fmaf(xa[i], wa[j], acc[i][j]);
    }

    #pragma unroll
    for (int i = 0; i < 4; ++i) {
        int row = rowbase + r0 + i;
        if (row < n)
            *(float4*)&out[(size_t)row * 64 + c0] =
                make_float4(acc[i][0], acc[i][1], acc[i][2], acc[i][3]);
    }
}

// ---------------- aggregation: one wave per dst node, register accumulation ----------------
__global__ void k_gather(const int2* __restrict__ cs2, const int* __restrict__ rowptr,
                         const float* __restrict__ dis, const float* __restrict__ t,
                         int n, float* __restrict__ a) {
    int lane = threadIdx.x & 63;
    int wave = threadIdx.x >> 6;
    int row = blockIdx.x * 4 + wave;
    if (row >= n) return;
    int e0 = rowptr[row], e1 = rowptr[row + 1];
    float acc = 0.f;
    for (int base = e0; base < e1; base += 64) {
        int cnt = min(64, e1 - base);
        int2 p = (lane < cnt) ? cs2[base + lane] : make_int2(0, 0);
        for (int j = 0; j < cnt; ++j) {
            int   s = __shfl(p.x, j);
            float w = __int_as_float(__shfl(p.y, j));
            acc = fmaf(t[(size_t)s * 64 + lane], w, acc);
        }
    }
    float d = dis[row];
    a[(size_t)row * 64 + lane] = fmaf(t[(size_t)row * 64 + lane], d * d, acc);
}

// ---------------- BatchNorm stats ----------------
__global__ void k_stats(const float* __restrict__ a, int n, float* __restrict__ stats) {
    int c = threadIdx.x & 63;
    int grp = threadIdx.x >> 6;
    float s = 0.f, s2 = 0.f;
    for (int r = blockIdx.x * 4 + grp; r < n; r += gridDim.x * 4) {
        float v = a[(size_t)r * 64 + c];
        s += v; s2 += v * v;
    }
    __shared__ float sh[2][4][64];
    sh[0][grp][c] = s; sh[1][grp][c] = s2;
    __syncthreads();
    if (threadIdx.x < 64) {
        float S  = sh[0][0][c] + sh[0][1][c] + sh[0][2][c] + sh[0][3][c];
        float S2 = sh[1][0][c] + sh[1][1][c] + sh[1][2][c] + sh[1][3][c];
        atomicAdd(&stats[c], S);
        atomicAdd(&stats[64 + c], S2);
    }
}

__global__ void k_bnparams(const float* __restrict__ stats, const float* __restrict__ g,
                           const float* __restrict__ bt, int n, float* __restrict__ bnp) {
    int c = threadIdx.x;
    if (c < 64) {
        float inv_n = 1.f / (float)n;
        float mean = stats[c] * inv_n;
        float var = stats[64 + c] * inv_n - mean * mean;
        float s = g[c] * rsqrtf(var + BN_EPS);
        bnp[c] = s;
        bnp[64 + c] = bt[c] - mean * s;
    }
}

// ---------------- global mean pool: sorted batch -> segmented reduction ----------------
__global__ void k_gbound(const int* __restrict__ batch, int n, int G, int* __restrict__ gs) {
    int g = blockIdx.x * blockDim.x + threadIdx.x;
    if (g > G) return;
    int lo = 0, hi = n;                 // lower_bound: first i with batch[i] >= g
    while (lo < hi) { int mid = (lo + hi) >> 1; if (batch[mid] < g) lo = mid + 1; else hi = mid; }
    gs[g] = lo;
}

__global__ void k_pool2(const float* __restrict__ a, const float* __restrict__ bnp,
                        const int* __restrict__ gs, int G, float* __restrict__ out) {
    int lane = threadIdx.x & 63;
    int wave = threadIdx.x >> 6;
    int g = blockIdx.x * 4 + wave;
    if (g >= G) return;
    int s = gs[g], e = gs[g + 1];
    float sc = bnp[lane], of = bnp[64 + lane];
    float acc = 0.f;
    for (int r = s; r < e; ++r)
        acc += fmaxf(0.f, fmaf(a[(size_t)r * 64 + lane], sc, of));
    out[(size_t)g * 64 + lane] = acc / (float)max(e - s, 1);
}

// ---------------- launch ----------------
extern "C" void kernel_launch(void* const* d_in, const int* in_sizes, int n_in,
                              void* d_out, int out_size, void* d_ws, size_t ws_size,
                              hipStream_t stream) {
    const float* x     = (const float*)d_in[0];
    const int*   ei    = (const int*)d_in[1];
    const int*   batch = (const int*)d_in[2];
    const float* W1    = (const float*)d_in[3];
    const float* g1    = (const float*)d_in[5];
    const float* bt1   = (const float*)d_in[6];
    const float* W2    = (const float*)d_in[7];
    const float* g2    = (const float*)d_in[9];
    const float* bt2   = (const float*)d_in[10];

    const int N = in_sizes[0] / 64;
    const int E = in_sizes[1] / 2;
    const int G = out_size / 64;

    const int* src = ei;
    const int* dst = ei + E;

    float* t       = (float*)d_ws;                      // N*64
    float* a       = t + (size_t)N * 64;                // N*64
    int2*  cs2     = (int2*)(a + (size_t)N * 64);       // E
    float* dis     = (float*)(cs2 + E);                 // N
    int*   deg     = (int*)(dis + N);                   // N
    int*   rowptr  = deg + N;                           // N+1
    int*   nextpos = rowptr + N + 1;                    // N
    int*   bsum    = nextpos + N;                       // <=1024
    float* stats   = (float*)(bsum + 1024);             // 128
    float* bnp     = stats + 128;                       // 128
    int*   gs      = (int*)(bnp + 128);                 // G+1

    float* out = (float*)d_out;

    const int NBLK = (N + 1023) / 1024;
    const int mmBlocks = (N + 63) / 64;
    const int gaBlocks = (N + 3) / 4;

    // ---- degree / norm / CSR build / graph bounds ----
    hipMemsetAsync(deg, 0, (size_t)N * sizeof(int), stream);
    k_count_deg<<<(E + 255) / 256, 256, 0, stream>>>(dst, E, deg);
    k_dis<<<(N + 255) / 256, 256, 0, stream>>>(deg, N, dis);
    k_scanA<<<NBLK, 256, 0, stream>>>(deg, N, bsum);
    k_scanB<<<1, 64, 0, stream>>>(bsum, NBLK);
    k_scanC<<<NBLK, 256, 0, stream>>>(deg, bsum, N, E, rowptr, nextpos);
    k_fill<<<(E + 255) / 256, 256, 0, stream>>>(src, dst, dis, E, nextpos, cs2);
    k_gbound<<<(G + 256) / 256, 256, 0, stream>>>(batch, N, G, gs);

    // ---- layer 1 ----
    k_matmul64t<<<mmBlocks, 256, 0, stream>>>(x, W1, nullptr, N, t);
    k_gather<<<gaBlocks, 256, 0, stream>>>(cs2, rowptr, dis, t, N, a);
    hipMemsetAsync(stats, 0, 128 * sizeof(float), stream);
    k_stats<<<512, 256, 0, stream>>>(a, N, stats);
    k_bnparams<<<1, 64, 0, stream>>>(stats, g1, bt1, N, bnp);

    // ---- layer 2 (BN+ReLU of layer 1 fused into matmul input) ----
    k_matmul64t<<<mmBlocks, 256, 0, stream>>>(a, W2, bnp, N, t);
    k_gather<<<gaBlocks, 256, 0, stream>>>(cs2, rowptr, dis, t, N, a);
    hipMemsetAsync(stats, 0, 128 * sizeof(float), stream);
    k_stats<<<512, 256, 0, stream>>>(a, N, stats);
    k_bnparams<<<1, 64, 0, stream>>>(stats, g2, bt2, N, bnp);

    // ---- pool (BN+ReLU of layer 2 fused) ----
    k_pool2<<<(G + 3) / 4, 256, 0, stream>>>(a, bnp, gs, G, out);
}

// Round 4
// 447.259 us; speedup vs baseline: 2.5468x; 1.1554x over previous
//
#include <hip/hip_runtime.h>
#include <hip/hip_bf16.h>

#define BN_EPS 1e-5f

// bf16 <-> f32 helpers (bit ops; bf16->f32 exact, f32->bf16 RNE)
__device__ __forceinline__ float bf2f(ushort u) {
    return __uint_as_float(((unsigned int)u) << 16);
}
__device__ __forceinline__ ushort f2bf(float f) {
    unsigned int u = __float_as_uint(f);
    u += 0x7FFFu + ((u >> 16) & 1u);
    return (ushort)(u >> 16);
}

// ---------------- degree / normalization ----------------
__global__ void k_count_deg(const int* __restrict__ dst, int E, int* __restrict__ deg) {
    int i = blockIdx.x * blockDim.x + threadIdx.x;
    if (i < E) atomicAdd(&deg[dst[i]], 1);
}

__global__ void k_dis(const int* __restrict__ deg, int n, float* __restrict__ dis) {
    int i = blockIdx.x * blockDim.x + threadIdx.x;
    if (i < n) dis[i] = rsqrtf((float)(deg[i] + 1));   // +1 self-loop
}

// ---------------- CSR build: exclusive scan of deg ----------------
__global__ void k_scanA(const int* __restrict__ deg, int n, int* __restrict__ bsum) {
    __shared__ int sh[256];
    int base = blockIdx.x * 1024 + threadIdx.x * 4;
    int s = 0;
    #pragma unroll
    for (int k = 0; k < 4; ++k) { int i = base + k; if (i < n) s += deg[i]; }
    sh[threadIdx.x] = s;
    __syncthreads();
    for (int off = 128; off > 0; off >>= 1) {
        if (threadIdx.x < off) sh[threadIdx.x] += sh[threadIdx.x + off];
        __syncthreads();
    }
    if (threadIdx.x == 0) bsum[blockIdx.x] = sh[0];
}

__global__ void k_scanB(int* __restrict__ bsum, int nb) {
    if (threadIdx.x == 0) {
        int run = 0;
        for (int i = 0; i < nb; ++i) { int v = bsum[i]; bsum[i] = run; run += v; }
    }
}

__global__ void k_scanC(const int* __restrict__ deg, const int* __restrict__ bsum,
                        int n, int E, int* __restrict__ rowptr, int* __restrict__ nextpos) {
    __shared__ int sh[256];
    int tid = threadIdx.x;
    int base = blockIdx.x * 1024 + tid * 4;
    int v[4]; int tsum = 0;
    #pragma unroll
    for (int k = 0; k < 4; ++k) {
        int i = base + k;
        v[k] = (i < n) ? deg[i] : 0;
        tsum += v[k];
    }
    sh[tid] = tsum;
    __syncthreads();
    for (int off = 1; off < 256; off <<= 1) {
        int add = (tid >= off) ? sh[tid - off] : 0;
        __syncthreads();
        sh[tid] += add;
        __syncthreads();
    }
    int excl = bsum[blockIdx.x] + sh[tid] - tsum;
    #pragma unroll
    for (int k = 0; k < 4; ++k) {
        int i = base + k;
        if (i < n) { rowptr[i] = excl; nextpos[i] = excl; }
        excl += v[k];
    }
    if (blockIdx.x == 0 && tid == 0) rowptr[n] = E;
}

__global__ void k_fill(const int* __restrict__ src, const int* __restrict__ dst,
                       const float* __restrict__ dis, int E,
                       int* __restrict__ nextpos, int2* __restrict__ cs2) {
    int i = blockIdx.x * blockDim.x + threadIdx.x;
    if (i < E) {
        int s = src[i], d = dst[i];
        float w = dis[s] * dis[d];
        int pos = atomicAdd(&nextpos[d], 1);
        cs2[pos] = make_int2(s, __float_as_int(w));
    }
}

// ---------------- tiled dense transform: tb[64-tile][64] = f(X)[64-tile][64] @ W (bf16 out) ----
__global__ void k_matmul64t(const float* __restrict__ X, const float* __restrict__ W,
                            const float* __restrict__ bnp, int n, ushort* __restrict__ tb) {
    __shared__ float Xs[64][68];
    __shared__ float Ws[64][64];
    const int tid = threadIdx.x;
    const int rowbase = blockIdx.x * 64;

    {
        const float4* W4 = (const float4*)W;
        float4* Ws4 = (float4*)&Ws[0][0];
        #pragma unroll
        for (int k = 0; k < 4; ++k) Ws4[tid + 256 * k] = W4[tid + 256 * k];
    }
    {
        const int r  = tid >> 2;
        const int c0 = (tid & 3) * 16;
        const int row = rowbase + r;
        #pragma unroll
        for (int j = 0; j < 4; ++j) {
            float4 v;
            if (row < n) v = *(const float4*)&X[(size_t)row * 64 + c0 + 4 * j];
            else v = make_float4(0.f, 0.f, 0.f, 0.f);
            float vv[4] = {v.x, v.y, v.z, v.w};
            #pragma unroll
            for (int i = 0; i < 4; ++i) {
                int c = c0 + 4 * j + i;
                float f = vv[i];
                if (bnp) f = fmaxf(0.f, fmaf(f, bnp[c], bnp[64 + c]));
                Xs[c][r] = f;
            }
        }
    }
    __syncthreads();

    const int r0 = (tid & 15) * 4;
    const int c0 = (tid >> 4) * 4;
    float acc[4][4];
    #pragma unroll
    for (int i = 0; i < 4; ++i)
        #pragma unroll
        for (int j = 0; j < 4; ++j) acc[i][j] = 0.f;

    #pragma unroll 4
    for (int k = 0; k < 64; ++k) {
        float4 xv = *(const float4*)&Xs[k][r0];
        float4 wv = *(const float4*)&Ws[k][c0];
        float xa[4] = {xv.x, xv.y, xv.z, xv.w};
        float wa[4] = {wv.x, wv.y, wv.z, wv.w};
        #pragma unroll
        for (int i = 0; i < 4; ++i)
            #pragma unroll
            for (int j = 0; j < 4; ++j)
                acc[i][j] = fmaf(xa[i], wa[j], acc[i][j]);
    }

    #pragma unroll
    for (int i = 0; i < 4; ++i) {
        int row = rowbase + r0 + i;
        if (row < n) {
            ushort4 o;
            o.x = f2bf(acc[i][0]); o.y = f2bf(acc[i][1]);
            o.z = f2bf(acc[i][2]); o.w = f2bf(acc[i][3]);
            *(ushort4*)&tb[(size_t)row * 64 + c0] = o;
        }
    }
}

// ---------------- aggregation: one wave per dst node, 2 edges/iter via half-waves ----------------
__global__ void k_gather(const int2* __restrict__ cs2, const int* __restrict__ rowptr,
                         const float* __restrict__ dis, const ushort* __restrict__ tb,
                         int n, float* __restrict__ a) {
    int lane = threadIdx.x & 63;
    int wave = threadIdx.x >> 6;
    int row = blockIdx.x * 4 + wave;
    if (row >= n) return;
    const int hl = lane & 31;      // feature pair index
    const int half = lane >> 5;    // which edge of the pair
    int e0 = rowptr[row], e1 = rowptr[row + 1];
    float ax = 0.f, ay = 0.f;
    for (int base = e0; base < e1; base += 64) {
        int cnt = min(64, e1 - base);
        int2 p = (lane < cnt) ? cs2[base + lane] : make_int2(0, 0);
        int npair = (cnt + 1) >> 1;
        for (int j = 0; j < npair; ++j) {
            int idx = 2 * j + half;                    // lanes<32: even edge, lanes>=32: odd edge
            int   s = __shfl(p.x, idx);
            float w = __int_as_float(__shfl(p.y, idx)); // zero-padded beyond cnt
            ushort2 tv = *(const ushort2*)&tb[(size_t)s * 64 + 2 * hl];
            ax = fmaf(bf2f(tv.x), w, ax);
            ay = fmaf(bf2f(tv.y), w, ay);
        }
    }
    ax += __shfl_xor(ax, 32);
    ay += __shfl_xor(ay, 32);
    if (half == 0) {
        float d = dis[row];
        float d2 = d * d;
        ushort2 ts = *(const ushort2*)&tb[(size_t)row * 64 + 2 * hl];
        ax = fmaf(bf2f(ts.x), d2, ax);
        ay = fmaf(bf2f(ts.y), d2, ay);
        *(float2*)&a[(size_t)row * 64 + 2 * hl] = make_float2(ax, ay);
    }
}

// ---------------- BatchNorm stats ----------------
__global__ void k_stats(const float* __restrict__ a, int n, float* __restrict__ stats) {
    int c = threadIdx.x & 63;
    int grp = threadIdx.x >> 6;
    float s = 0.f, s2 = 0.f;
    for (int r = blockIdx.x * 4 + grp; r < n; r += gridDim.x * 4) {
        float v = a[(size_t)r * 64 + c];
        s += v; s2 += v * v;
    }
    __shared__ float sh[2][4][64];
    sh[0][grp][c] = s; sh[1][grp][c] = s2;
    __syncthreads();
    if (threadIdx.x < 64) {
        float S  = sh[0][0][c] + sh[0][1][c] + sh[0][2][c] + sh[0][3][c];
        float S2 = sh[1][0][c] + sh[1][1][c] + sh[1][2][c] + sh[1][3][c];
        atomicAdd(&stats[c], S);
        atomicAdd(&stats[64 + c], S2);
    }
}

__global__ void k_bnparams(const float* __restrict__ stats, const float* __restrict__ g,
                           const float* __restrict__ bt, int n, float* __restrict__ bnp) {
    int c = threadIdx.x;
    if (c < 64) {
        float inv_n = 1.f / (float)n;
        float mean = stats[c] * inv_n;
        float var = stats[64 + c] * inv_n - mean * mean;
        float s = g[c] * rsqrtf(var + BN_EPS);
        bnp[c] = s;
        bnp[64 + c] = bt[c] - mean * s;
    }
}

// ---------------- global mean pool: sorted batch -> segmented reduction ----------------
__global__ void k_gbound(const int* __restrict__ batch, int n, int G, int* __restrict__ gs) {
    int g = blockIdx.x * blockDim.x + threadIdx.x;
    if (g > G) return;
    int lo = 0, hi = n;
    while (lo < hi) { int mid = (lo + hi) >> 1; if (batch[mid] < g) lo = mid + 1; else hi = mid; }
    gs[g] = lo;
}

__global__ void k_pool2(const float* __restrict__ a, const float* __restrict__ bnp,
                        const int* __restrict__ gs, int G, float* __restrict__ out) {
    int lane = threadIdx.x & 63;
    int wave = threadIdx.x >> 6;
    int g = blockIdx.x * 4 + wave;
    if (g >= G) return;
    int s = gs[g], e = gs[g + 1];
    float sc = bnp[lane], of = bnp[64 + lane];
    float acc = 0.f;
    for (int r = s; r < e; ++r)
        acc += fmaxf(0.f, fmaf(a[(size_t)r * 64 + lane], sc, of));
    out[(size_t)g * 64 + lane] = acc / (float)max(e - s, 1);
}

// ---------------- launch ----------------
extern "C" void kernel_launch(void* const* d_in, const int* in_sizes, int n_in,
                              void* d_out, int out_size, void* d_ws, size_t ws_size,
                              hipStream_t stream) {
    const float* x     = (const float*)d_in[0];
    const int*   ei    = (const int*)d_in[1];
    const int*   batch = (const int*)d_in[2];
    const float* W1    = (const float*)d_in[3];
    const float* g1    = (const float*)d_in[5];
    const float* bt1   = (const float*)d_in[6];
    const float* W2    = (const float*)d_in[7];
    const float* g2    = (const float*)d_in[9];
    const float* bt2   = (const float*)d_in[10];

    const int N = in_sizes[0] / 64;
    const int E = in_sizes[1] / 2;
    const int G = out_size / 64;

    const int* src = ei;
    const int* dst = ei + E;

    ushort* tb     = (ushort*)d_ws;                     // N*64 bf16
    float* a       = (float*)(tb + (size_t)N * 64);     // N*64 f32
    int2*  cs2     = (int2*)(a + (size_t)N * 64);       // E
    float* dis     = (float*)(cs2 + E);                 // N
    int*   deg     = (int*)(dis + N);                   // N
    int*   rowptr  = deg + N;                           // N+1
    int*   nextpos = rowptr + N + 1;                    // N
    int*   bsum    = nextpos + N;                       // <=1024
    float* stats   = (float*)(bsum + 1024);             // 128
    float* bnp     = stats + 128;                       // 128
    int*   gs      = (int*)(bnp + 128);                 // G+1

    float* out = (float*)d_out;

    const int NBLK = (N + 1023) / 1024;
    const int mmBlocks = (N + 63) / 64;
    const int gaBlocks = (N + 3) / 4;

    // ---- degree / norm / CSR build / graph bounds ----
    hipMemsetAsync(deg, 0, (size_t)N * sizeof(int), stream);
    k_count_deg<<<(E + 255) / 256, 256, 0, stream>>>(dst, E, deg);
    k_dis<<<(N + 255) / 256, 256, 0, stream>>>(deg, N, dis);
    k_scanA<<<NBLK, 256, 0, stream>>>(deg, N, bsum);
    k_scanB<<<1, 64, 0, stream>>>(bsum, NBLK);
    k_scanC<<<NBLK, 256, 0, stream>>>(deg, bsum, N, E, rowptr, nextpos);
    k_fill<<<(E + 255) / 256, 256, 0, stream>>>(src, dst, dis, E, nextpos, cs2);
    k_gbound<<<(G + 256) / 256, 256, 0, stream>>>(batch, N, G, gs);

    // ---- layer 1 ----
    k_matmul64t<<<mmBlocks, 256, 0, stream>>>(x, W1, nullptr, N, tb);
    k_gather<<<gaBlocks, 256, 0, stream>>>(cs2, rowptr, dis, tb, N, a);
    hipMemsetAsync(stats, 0, 128 * sizeof(float), stream);
    k_stats<<<512, 256, 0, stream>>>(a, N, stats);
    k_bnparams<<<1, 64, 0, stream>>>(stats, g1, bt1, N, bnp);

    // ---- layer 2 (BN+ReLU of layer 1 fused into matmul input) ----
    k_matmul64t<<<mmBlocks, 256, 0, stream>>>(a, W2, bnp, N, tb);
    k_gather<<<gaBlocks, 256, 0, stream>>>(cs2, rowptr, dis, tb, N, a);
    hipMemsetAsync(stats, 0, 128 * sizeof(float), stream);
    k_stats<<<512, 256, 0, stream>>>(a, N, stats);
    k_bnparams<<<1, 64, 0, stream>>>(stats, g2, bt2, N, bnp);

    // ---- pool (BN+ReLU of layer 2 fused) ----
    k_pool2<<<(G + 3) / 4, 256, 0, stream>>>(a, bnp, gs, G, out);
}